// Round 1
// baseline (588.007 us; speedup 1.0000x reference)
//
#include <hip/hip_runtime.h>

// Problem constants (fixed by reference: shape (2,1,160,160,160) fp32)
#define DIMX 160
#define DIMY 160
#define DIMZ 160
#define BC   2
#define NTOT (BC * DIMZ * DIMY * DIMX)   // 8,192,000
#define WIN  11
#define PAD  5
#define SEG  20
#define NSEG (DIMZ / SEG)                 // 8

static_assert(NTOT == 8192000, "size mismatch");

// block = 256 threads = 4 waves
__device__ __forceinline__ void block_reduce_add(float v, double* acc) {
#pragma unroll
    for (int off = 32; off > 0; off >>= 1) v += __shfl_down(v, off, 64);
    __shared__ float smem[4];
    int lane = threadIdx.x & 63;
    int wv   = threadIdx.x >> 6;
    if (lane == 0) smem[wv] = v;
    __syncthreads();
    if (threadIdx.x == 0) {
        atomicAdd(acc, (double)(smem[0] + smem[1] + smem[2] + smem[3]));
    }
}

// K1: box-sum along W for 5 fields {x,y,xx,yy,xy}; fused smooth-L1 reduction.
__global__ __launch_bounds__(256) void k1_wpass(const float* __restrict__ X,
                                                const float* __restrict__ Y,
                                                float* __restrict__ A,
                                                double* __restrict__ acc) {
    int n = blockIdx.x * 256 + threadIdx.x;   // grid sized exactly NTOT/256
    int w = n % DIMX;
    float sx = 0.f, sy = 0.f, sxx = 0.f, syy = 0.f, sxy = 0.f;
#pragma unroll
    for (int j = -PAD; j <= PAD; ++j) {
        int wj = w + j;
        if ((unsigned)wj < (unsigned)DIMX) {
            float xv = X[n + j];
            float yv = Y[n + j];
            sx  += xv;      sy  += yv;
            sxx += xv * xv; syy += yv * yv; sxy += xv * yv;
        }
    }
    A[0 * (size_t)NTOT + n] = sx;
    A[1 * (size_t)NTOT + n] = sy;
    A[2 * (size_t)NTOT + n] = sxx;
    A[3 * (size_t)NTOT + n] = syy;
    A[4 * (size_t)NTOT + n] = sxy;

    float xv0 = X[n], yv0 = Y[n];
    float d  = fabsf(xv0 - yv0);
    float l1 = (d < 1.0f) ? (0.5f * d * d) : (d - 0.5f);
    block_reduce_add(l1, acc + 0);
}

// K2: box-sum along H, in-place on A. One thread owns one (field,b,d,w) line.
// Shift-register window (fully unrolled -> registers, no scratch).
__global__ __launch_bounds__(256) void k2_hpass(float* __restrict__ A) {
    const int LINES = BC * DIMZ * DIMX;  // 51200 lines per field
    int tid = blockIdx.x * 256 + threadIdx.x;
    int f = tid / LINES;
    int r = tid - f * LINES;
    int w = r % DIMX;
    int t = r / DIMX;
    int d = t % DIMZ;
    int b = t / DIMZ;
    float* p = A + (size_t)f * NTOT + (size_t)(b * DIMZ + d) * (DIMY * DIMX) + w;

    float win[WIN];
#pragma unroll
    for (int j = 0; j < WIN; ++j) win[j] = 0.f;
    float sum = 0.f;
#pragma unroll
    for (int j = 0; j < PAD; ++j) {          // preload in[0..4]
        float v = p[j * DIMX];
        win[PAD + 1 + j] = v;                // slots 6..10
        sum += v;
    }
    for (int h = 0; h < DIMY; ++h) {
        float newv = (h + PAD < DIMY) ? p[(h + PAD) * DIMX] : 0.f;
        sum += newv - win[0];                // win[0] == in[h-6] (0 when h<6)
#pragma unroll
        for (int j = 0; j < WIN - 1; ++j) win[j] = win[j + 1];
        win[WIN - 1] = newv;
        p[h * DIMX] = sum;                   // position h never re-read later
    }
}

// K3: box-sum along D (sliding add/sub, old value re-read from L2),
// SSIM per voxel, block reduction into acc[1].
__global__ __launch_bounds__(256) void k3_dpass(const float* __restrict__ A,
                                                double* __restrict__ acc) {
    int tid = blockIdx.x * 256 + threadIdx.x;
    int w   = tid % DIMX;
    int t   = tid / DIMX;
    int h   = t % DIMY;
    int t2  = t / DIMY;
    int b   = t2 % BC;
    int seg = t2 / BC;
    int d0  = seg * SEG;

    const size_t strideD = (size_t)DIMY * DIMX;  // 25600
    const float* p = A + (size_t)b * (DIMZ * DIMY * DIMX) + (size_t)h * DIMX + w;

    float s[5] = {0.f, 0.f, 0.f, 0.f, 0.f};
    // Prefill: sum over [d0-6, d0+4] (valid entries), so the first loop
    // iteration's add/sub yields the window [d0-5, d0+5].
    for (int j = d0 - 6; j <= d0 + 4; ++j) {
        if ((unsigned)j < (unsigned)DIMZ) {
#pragma unroll
            for (int f = 0; f < 5; ++f) s[f] += p[(size_t)f * NTOT + (size_t)j * strideD];
        }
    }

    const float inv = 1.0f / 1331.0f;             // 1/11^3
    const float c1  = 0.01f / (4096.f * 4096.f);  // K1 / data_range^2 (faithful)
    const float c2  = 0.03f / (4096.f * 4096.f);
    float lsum = 0.f;

    for (int d = d0; d < d0 + SEG; ++d) {
        int ja = d + PAD;
        int js = d - PAD - 1;
        if (ja < DIMZ) {
#pragma unroll
            for (int f = 0; f < 5; ++f) s[f] += p[(size_t)f * NTOT + (size_t)ja * strideD];
        }
        if (js >= 0) {
#pragma unroll
            for (int f = 0; f < 5; ++f) s[f] -= p[(size_t)f * NTOT + (size_t)js * strideD];
        }
        float mux = s[0] * inv, muy = s[1] * inv;
        float exx = s[2] * inv, eyy = s[3] * inv, exy = s[4] * inv;
        float mux2 = mux * mux, muy2 = muy * muy, muxy = mux * muy;
        float vx = exx - mux2, vy = eyy - muy2, vxy = exy - muxy;
        float nnum = (2.f * muxy + c1) * (2.f * vxy + c2);
        float dden = (mux2 + muy2 + c1) * (vx + vy + c2);
        float ssim = nnum / (dden + 1e-8f);
        float val  = 0.5f * (1.f - ssim);
        val = fminf(fmaxf(val, 0.f), 1.f);
        lsum += val;
    }
    block_reduce_add(lsum, acc + 1);
}

// K4: combine into the scalar output.
__global__ void k4_final(const double* __restrict__ acc, float* __restrict__ out) {
    double invN = 1.0 / (double)NTOT;
    double l1m  = acc[0] * invN;
    double ssm  = acc[1] * invN;
    out[0] = (float)(0.85 * ssm + 0.15 * l1m);
}

extern "C" void kernel_launch(void* const* d_in, const int* in_sizes, int n_in,
                              void* d_out, int out_size, void* d_ws, size_t ws_size,
                              hipStream_t stream) {
    const float* X = (const float*)d_in[0];
    const float* Y = (const float*)d_in[1];
    float* out = (float*)d_out;

    float*  A   = (float*)d_ws;                                   // 5*NTOT floats
    double* acc = (double*)((char*)d_ws + (size_t)5 * NTOT * 4);  // 2 doubles

    hipMemsetAsync(acc, 0, 2 * sizeof(double), stream);

    k1_wpass<<<NTOT / 256, 256, 0, stream>>>(X, Y, A, acc);
    k2_hpass<<<(5 * BC * DIMZ * DIMX) / 256, 256, 0, stream>>>(A);
    k3_dpass<<<(NSEG * BC * DIMY * DIMX) / 256, 256, 0, stream>>>(A, acc);
    k4_final<<<1, 1, 0, stream>>>(acc, out);
}

// Round 2
// 347.026 us; speedup vs baseline: 1.6944x; 1.6944x over previous
//
#include <hip/hip_runtime.h>

// Problem constants (fixed by reference: shape (2,1,160,160,160) fp32)
#define DIMX 160
#define DIMY 160
#define DIMZ 160
#define BC   2
#define NTOT (BC * DIMZ * DIMY * DIMX)   // 8,192,000
#define WIN  11
#define PAD  5
#define SEG  20
#define NSEG (DIMZ / SEG)                 // 8
#define NB1  (NTOT / 256)                 // 32000 k1 blocks
#define NB3  ((NSEG * BC * DIMY * DIMX) / 256)  // 1600 k3 blocks

static_assert(NTOT == 8192000, "size mismatch");

// Block (256 thr) sum -> returns total on thread 0 (garbage elsewhere).
__device__ __forceinline__ float block_sum256(float v) {
#pragma unroll
    for (int off = 32; off > 0; off >>= 1) v += __shfl_down(v, off, 64);
    __shared__ float smem[4];
    int lane = threadIdx.x & 63;
    int wv   = threadIdx.x >> 6;
    if (lane == 0) smem[wv] = v;
    __syncthreads();
    return smem[0] + smem[1] + smem[2] + smem[3];
}

// K1: box-sum along W for 5 fields {x,y,xx,yy,xy}; fused smooth-L1 reduction.
// ATOMIC=false: per-block partial into p1[blockIdx.x] (no same-address atomics).
template <bool ATOMIC>
__global__ __launch_bounds__(256) void k1_wpass(const float* __restrict__ X,
                                                const float* __restrict__ Y,
                                                float* __restrict__ A,
                                                float* __restrict__ p1,
                                                double* __restrict__ acc) {
    int n = blockIdx.x * 256 + threadIdx.x;   // grid sized exactly NTOT/256
    int w = n % DIMX;
    float sx = 0.f, sy = 0.f, sxx = 0.f, syy = 0.f, sxy = 0.f;
#pragma unroll
    for (int j = -PAD; j <= PAD; ++j) {
        int wj = w + j;
        if ((unsigned)wj < (unsigned)DIMX) {
            float xv = X[n + j];
            float yv = Y[n + j];
            sx  += xv;      sy  += yv;
            sxx += xv * xv; syy += yv * yv; sxy += xv * yv;
        }
    }
    A[0 * (size_t)NTOT + n] = sx;
    A[1 * (size_t)NTOT + n] = sy;
    A[2 * (size_t)NTOT + n] = sxx;
    A[3 * (size_t)NTOT + n] = syy;
    A[4 * (size_t)NTOT + n] = sxy;

    float xv0 = X[n], yv0 = Y[n];
    float d  = fabsf(xv0 - yv0);
    float l1 = (d < 1.0f) ? (0.5f * d * d) : (d - 0.5f);
    float tot = block_sum256(l1);
    if (threadIdx.x == 0) {
        if (ATOMIC) atomicAdd(acc, (double)tot);
        else        p1[blockIdx.x] = tot;
    }
}

// K2: box-sum along H, in-place on A. One thread owns one (field,b,d,w) line.
// Shift-register window (fully unrolled -> registers, no scratch).
__global__ __launch_bounds__(256) void k2_hpass(float* __restrict__ A) {
    const int LINES = BC * DIMZ * DIMX;  // 51200 lines per field
    int tid = blockIdx.x * 256 + threadIdx.x;
    int f = tid / LINES;
    int r = tid - f * LINES;
    int w = r % DIMX;
    int t = r / DIMX;
    int d = t % DIMZ;
    int b = t / DIMZ;
    float* p = A + (size_t)f * NTOT + (size_t)(b * DIMZ + d) * (DIMY * DIMX) + w;

    float win[WIN];
#pragma unroll
    for (int j = 0; j < WIN; ++j) win[j] = 0.f;
    float sum = 0.f;
#pragma unroll
    for (int j = 0; j < PAD; ++j) {          // preload in[0..4]
        float v = p[j * DIMX];
        win[PAD + 1 + j] = v;                // slots 6..10
        sum += v;
    }
    for (int h = 0; h < DIMY; ++h) {
        float newv = (h + PAD < DIMY) ? p[(h + PAD) * DIMX] : 0.f;
        sum += newv - win[0];                // win[0] == in[h-6] (0 when h<6)
#pragma unroll
        for (int j = 0; j < WIN - 1; ++j) win[j] = win[j + 1];
        win[WIN - 1] = newv;
        p[h * DIMX] = sum;                   // position h never re-read later
    }
}

// K3: box-sum along D (sliding add/sub, old value re-read from L2),
// SSIM per voxel, per-block partial into p3 (or atomic fallback).
template <bool ATOMIC>
__global__ __launch_bounds__(256) void k3_dpass(const float* __restrict__ A,
                                                float* __restrict__ p3,
                                                double* __restrict__ acc) {
    int tid = blockIdx.x * 256 + threadIdx.x;
    int w   = tid % DIMX;
    int t   = tid / DIMX;
    int h   = t % DIMY;
    int t2  = t / DIMY;
    int b   = t2 % BC;
    int seg = t2 / BC;
    int d0  = seg * SEG;

    const size_t strideD = (size_t)DIMY * DIMX;  // 25600
    const float* p = A + (size_t)b * (DIMZ * DIMY * DIMX) + (size_t)h * DIMX + w;

    float s[5] = {0.f, 0.f, 0.f, 0.f, 0.f};
    // Prefill: sum over [d0-6, d0+4] (valid entries), so the first loop
    // iteration's add/sub yields the window [d0-5, d0+5].
    for (int j = d0 - 6; j <= d0 + 4; ++j) {
        if ((unsigned)j < (unsigned)DIMZ) {
#pragma unroll
            for (int f = 0; f < 5; ++f) s[f] += p[(size_t)f * NTOT + (size_t)j * strideD];
        }
    }

    const float inv = 1.0f / 1331.0f;             // 1/11^3
    const float c1  = 0.01f / (4096.f * 4096.f);  // K1 / data_range^2 (faithful)
    const float c2  = 0.03f / (4096.f * 4096.f);
    float lsum = 0.f;

    for (int d = d0; d < d0 + SEG; ++d) {
        int ja = d + PAD;
        int js = d - PAD - 1;
        if (ja < DIMZ) {
#pragma unroll
            for (int f = 0; f < 5; ++f) s[f] += p[(size_t)f * NTOT + (size_t)ja * strideD];
        }
        if (js >= 0) {
#pragma unroll
            for (int f = 0; f < 5; ++f) s[f] -= p[(size_t)f * NTOT + (size_t)js * strideD];
        }
        float mux = s[0] * inv, muy = s[1] * inv;
        float exx = s[2] * inv, eyy = s[3] * inv, exy = s[4] * inv;
        float mux2 = mux * mux, muy2 = muy * muy, muxy = mux * muy;
        float vx = exx - mux2, vy = eyy - muy2, vxy = exy - muxy;
        float nnum = (2.f * muxy + c1) * (2.f * vxy + c2);
        float dden = (mux2 + muy2 + c1) * (vx + vy + c2);
        float ssim = nnum / (dden + 1e-8f);
        float val  = 0.5f * (1.f - ssim);
        val = fminf(fmaxf(val, 0.f), 1.f);
        lsum += val;
    }
    float tot = block_sum256(lsum);
    if (threadIdx.x == 0) {
        if (ATOMIC) atomicAdd(acc, (double)tot);
        else        p3[blockIdx.x] = tot;
    }
}

// K4a: reduce partial buffers (no-atomic path). One block, 256 threads.
__global__ __launch_bounds__(256) void k4_reduce(const float* __restrict__ p1,
                                                 const float* __restrict__ p3,
                                                 float* __restrict__ out) {
    double s1 = 0.0, s3 = 0.0;
    for (int i = threadIdx.x; i < NB1; i += 256) s1 += (double)p1[i];
    for (int i = threadIdx.x; i < NB3; i += 256) s3 += (double)p3[i];
#pragma unroll
    for (int off = 32; off > 0; off >>= 1) {
        s1 += __shfl_down(s1, off, 64);
        s3 += __shfl_down(s3, off, 64);
    }
    __shared__ double sm1[4], sm3[4];
    int lane = threadIdx.x & 63;
    int wv   = threadIdx.x >> 6;
    if (lane == 0) { sm1[wv] = s1; sm3[wv] = s3; }
    __syncthreads();
    if (threadIdx.x == 0) {
        double l1m = (sm1[0] + sm1[1] + sm1[2] + sm1[3]) / (double)NTOT;
        double ssm = (sm3[0] + sm3[1] + sm3[2] + sm3[3]) / (double)NTOT;
        out[0] = (float)(0.85 * ssm + 0.15 * l1m);
    }
}

// K4b: combine accumulators (atomic fallback path).
__global__ void k4_final(const double* __restrict__ acc, float* __restrict__ out) {
    double invN = 1.0 / (double)NTOT;
    double l1m  = acc[0] * invN;
    double ssm  = acc[1] * invN;
    out[0] = (float)(0.85 * ssm + 0.15 * l1m);
}

extern "C" void kernel_launch(void* const* d_in, const int* in_sizes, int n_in,
                              void* d_out, int out_size, void* d_ws, size_t ws_size,
                              hipStream_t stream) {
    const float* X = (const float*)d_in[0];
    const float* Y = (const float*)d_in[1];
    float* out = (float*)d_out;

    float* A = (float*)d_ws;                                 // 5*NTOT floats
    const size_t baseA = (size_t)5 * NTOT * sizeof(float);   // 163,840,000 B
    float*  p1  = (float*)((char*)d_ws + baseA);             // NB1 floats
    float*  p3  = p1 + NB1;                                  // NB3 floats
    const size_t need_part = baseA + (size_t)(NB1 + NB3) * sizeof(float);

    if (ws_size >= need_part) {
        // Preferred path: no same-address atomics anywhere.
        k1_wpass<false><<<NB1, 256, 0, stream>>>(X, Y, A, p1, nullptr);
        k2_hpass<<<(5 * BC * DIMZ * DIMX) / 256, 256, 0, stream>>>(A);
        k3_dpass<false><<<NB3, 256, 0, stream>>>(A, p3, nullptr);
        k4_reduce<<<1, 256, 0, stream>>>(p1, p3, out);
    } else {
        // Fallback (known-correct, slower): fp64 atomics into 2 accumulators.
        double* acc = (double*)((char*)d_ws + baseA);
        hipMemsetAsync(acc, 0, 2 * sizeof(double), stream);
        k1_wpass<true><<<NB1, 256, 0, stream>>>(X, Y, A, nullptr, acc);
        k2_hpass<<<(5 * BC * DIMZ * DIMX) / 256, 256, 0, stream>>>(A);
        k3_dpass<true><<<NB3, 256, 0, stream>>>(A, nullptr, acc);
        k4_final<<<1, 1, 0, stream>>>(acc, out);
    }
}

// Round 3
// 227.790 us; speedup vs baseline: 2.5814x; 1.5235x over previous
//
#include <hip/hip_runtime.h>

// Shape fixed by reference: (2,1,160,160,160) fp32, window 11, zero-pad box filter.
#define DIMX 160
#define DIMY 160
#define DIMZ 160
#define BC   2
#define NTOT (BC * DIMZ * DIMY * DIMX)   // 8,192,000
#define PAD  5
#define TS   16                  // tile size in H and W
#define HS   (TS + 2 * PAD)      // 26: tile + halo
#define XSTR 40                  // raw-slab LDS row stride (==8 mod 32 -> 2-way bank free)
#define CD   32                  // D-chunk per block
#define NCH  (DIMZ / CD)         // 5
#define NTH  (DIMY / TS)         // 10
#define NTW  (DIMX / TS)         // 10
#define NBLK (NCH * BC * NTH * NTW)  // 1000 blocks

static_assert(NTOT == 8192000, "size mismatch");
static_assert(DIMZ % CD == 0 && DIMY % TS == 0 && DIMX % TS == 0, "tiling mismatch");

// Ring slot update with compile-time index K (keeps ring[][] in VGPRs — no
// dynamic register indexing, no scratch).
#define RING_CASE(K) case K: {                                         \
    _Pragma("unroll")                                                  \
    for (int f = 0; f < 5; ++f) {                                      \
      sums[f] += S[f] - ring[K][f];                                    \
      ring[K][f] = S[f];                                               \
    }                                                                  \
  } break;

__global__ __launch_bounds__(256) void fused_ssim(const float* __restrict__ X,
                                                  const float* __restrict__ Y,
                                                  float* __restrict__ pssim,
                                                  float* __restrict__ pl1) {
  __shared__ float xsl[HS * XSTR];     // raw x slab (26 rows x stride 40)
  __shared__ float ysl[HS * XSTR];     // raw y slab
  __shared__ float wp[5][HS * TS];     // W-passed fields, [f][h*16+w]

  const int tid = threadIdx.x;
  const int bx  = blockIdx.x;
  const int tw  = bx % NTW;
  const int th  = (bx / NTW) % NTH;
  const int b   = (bx / (NTW * NTH)) % BC;
  const int ch  =  bx / (NTW * NTH * BC);
  const int h0  = th * TS;
  const int w0  = tw * TS;
  const int c0  = ch * CD;

  const size_t bbase = (size_t)b * DIMZ * DIMY * DIMX;

  const int hh = tid >> 4;     // this thread's tile row (0..15)
  const int ww = tid & 15;     // this thread's tile col (0..15)

  float ring[11][5];
#pragma unroll
  for (int k = 0; k < 11; ++k)
#pragma unroll
    for (int f = 0; f < 5; ++f) ring[k][f] = 0.f;
  float sums[5] = {0.f, 0.f, 0.f, 0.f, 0.f};
  float l1loc = 0.f, ssloc = 0.f;

  const float inv = 1.0f / 1331.0f;             // 1/11^3
  const float c1  = 0.01f / (4096.f * 4096.f);  // K1 / data_range^2 (faithful to ref)
  const float c2  = 0.03f / (4096.f * 4096.f);

  int ph = ((c0 - PAD) + 22) % 11;   // uniform ring phase; c0-5 >= -5 so +22 keeps it positive

  // March slabs d in [c0-5, c0+CD+4]; output voxel dc = d-5 when dc in [c0, c0+CD).
  for (int d = c0 - PAD; d <= c0 + CD + PAD - 1; ++d) {
    float S[5] = {0.f, 0.f, 0.f, 0.f, 0.f};
    if ((unsigned)d < (unsigned)DIMZ) {
      const size_t dbase = bbase + (size_t)d * (DIMY * DIMX);
      const bool dIn = (d >= c0) && (d < c0 + CD);

      __syncthreads();  // previous slab's H-pass readers must finish before restaging

      // --- stage raw x,y (zero global-OOB); fuse smooth-L1 on owned points ---
      for (int i = tid; i < HS * 32; i += 256) {
        int r = i >> 5, c = i & 31;
        if (c < HS) {
          int gh = h0 - PAD + r;
          int gw = w0 - PAD + c;
          bool in = ((unsigned)gh < (unsigned)DIMY) && ((unsigned)gw < (unsigned)DIMX);
          float xv = 0.f, yv = 0.f;
          if (in) {
            size_t g = dbase + (size_t)gh * DIMX + gw;
            xv = X[g];
            yv = Y[g];
          }
          xsl[r * XSTR + c] = xv;
          ysl[r * XSTR + c] = yv;
          if (dIn && r >= PAD && r < PAD + TS && c >= PAD && c < PAD + TS) {
            float ad = fabsf(xv - yv);
            l1loc += (ad < 1.f) ? 0.5f * ad * ad : ad - 0.5f;
          }
        }
      }
      __syncthreads();

      // --- W-pass: 11-tap sums of {x,y,xx,yy,xy} for all 26 halo rows x 16 cols ---
      for (int i = tid; i < HS * TS; i += 256) {
        int h = i >> 4, w = i & 15;
        float sx = 0.f, sy = 0.f, sxx = 0.f, syy = 0.f, sxy = 0.f;
#pragma unroll
        for (int j = 0; j <= 2 * PAD; ++j) {
          float xv = xsl[h * XSTR + w + j];
          float yv = ysl[h * XSTR + w + j];
          sx += xv;
          sy += yv;
          sxx = fmaf(xv, xv, sxx);
          syy = fmaf(yv, yv, syy);
          sxy = fmaf(xv, yv, sxy);
        }
        wp[0][i] = sx;
        wp[1][i] = sy;
        wp[2][i] = sxx;
        wp[3][i] = syy;
        wp[4][i] = sxy;
      }
      __syncthreads();

      // --- H-pass: 11 taps per field into registers (taps 64B apart -> ds_read2) ---
#pragma unroll
      for (int j = 0; j <= 2 * PAD; ++j) {
        int o = (hh + j) * TS + ww;
        S[0] += wp[0][o];
        S[1] += wp[1][o];
        S[2] += wp[2][o];
        S[3] += wp[3][o];
        S[4] += wp[4][o];
      }
    }

    // --- D-window ring update (registers, static index via uniform switch) ---
    switch (ph) {
      RING_CASE(0) RING_CASE(1) RING_CASE(2) RING_CASE(3) RING_CASE(4)
      RING_CASE(5) RING_CASE(6) RING_CASE(7) RING_CASE(8) RING_CASE(9)
      RING_CASE(10)
    }
    ph = (ph == 10) ? 0 : ph + 1;

    // --- SSIM for output voxel dc = d-5 (window [dc-5, dc+5] now in sums) ---
    if (d >= c0 + PAD) {
      float mux = sums[0] * inv, muy = sums[1] * inv;
      float exx = sums[2] * inv, eyy = sums[3] * inv, exy = sums[4] * inv;
      float mux2 = mux * mux, muy2 = muy * muy, muxy = mux * muy;
      float vx = exx - mux2, vy = eyy - muy2, vxy = exy - muxy;
      float nnum = (2.f * muxy + c1) * (2.f * vxy + c2);
      float dden = (mux2 + muy2 + c1) * (vx + vy + c2);
      float ssim = nnum / (dden + 1e-8f);
      float val  = 0.5f * (1.f - ssim);
      ssloc += fminf(fmaxf(val, 0.f), 1.f);
    }
  }

  // --- block reduction of (ssloc, l1loc) -> per-block partials ---
#pragma unroll
  for (int off = 32; off > 0; off >>= 1) {
    ssloc += __shfl_down(ssloc, off, 64);
    l1loc += __shfl_down(l1loc, off, 64);
  }
  __syncthreads();                 // done with LDS compute use; reuse xsl as scratch
  int lane = tid & 63, wv = tid >> 6;
  if (lane == 0) {
    xsl[wv * 2]     = ssloc;
    xsl[wv * 2 + 1] = l1loc;
  }
  __syncthreads();
  if (tid == 0) {
    pssim[bx] = xsl[0] + xsl[2] + xsl[4] + xsl[6];
    pl1[bx]   = xsl[1] + xsl[3] + xsl[5] + xsl[7];
  }
}

// Final: reduce 1000 + 1000 partials in double, emit scalar loss.
__global__ __launch_bounds__(256) void final_reduce(const float* __restrict__ pssim,
                                                    const float* __restrict__ pl1,
                                                    float* __restrict__ out) {
  double s = 0.0, l = 0.0;
  for (int i = threadIdx.x; i < NBLK; i += 256) {
    s += (double)pssim[i];
    l += (double)pl1[i];
  }
#pragma unroll
  for (int off = 32; off > 0; off >>= 1) {
    s += __shfl_down(s, off, 64);
    l += __shfl_down(l, off, 64);
  }
  __shared__ double sm[8];
  int lane = threadIdx.x & 63, wv = threadIdx.x >> 6;
  if (lane == 0) { sm[wv * 2] = s; sm[wv * 2 + 1] = l; }
  __syncthreads();
  if (threadIdx.x == 0) {
    double ssm = (sm[0] + sm[2] + sm[4] + sm[6]) / (double)NTOT;
    double l1m = (sm[1] + sm[3] + sm[5] + sm[7]) / (double)NTOT;
    out[0] = (float)(0.85 * ssm + 0.15 * l1m);
  }
}

extern "C" void kernel_launch(void* const* d_in, const int* in_sizes, int n_in,
                              void* d_out, int out_size, void* d_ws, size_t ws_size,
                              hipStream_t stream) {
  const float* X = (const float*)d_in[0];
  const float* Y = (const float*)d_in[1];
  float* out = (float*)d_out;

  float* pssim = (float*)d_ws;        // NBLK floats
  float* pl1   = pssim + NBLK;        // NBLK floats  (8 KB total, << ws_size)

  fused_ssim<<<NBLK, 256, 0, stream>>>(X, Y, pssim, pl1);
  final_reduce<<<1, 256, 0, stream>>>(pssim, pl1, out);
}

// Round 4
// 215.360 us; speedup vs baseline: 2.7303x; 1.0577x over previous
//
#include <hip/hip_runtime.h>

// Shape fixed by reference: (2,1,160,160,160) fp32, window 11, zero-pad box filter.
#define DIMX 160
#define DIMY 160
#define DIMZ 160
#define BC   2
#define NTOT (BC * DIMZ * DIMY * DIMX)   // 8,192,000
#define PAD  5
#define TS   16                  // tile size in H and W
#define HS   26                  // TS + 2*PAD rows
#define SC4  8                   // staged float4 per row (32 cols: w0-8 .. w0+23)
#define XS4  10                  // xs/ys row stride in float4 (40 words; 16B-aligned rows)
#define WPS  17                  // wp4/wp1 row stride (17 float4 / 17 floats; breaks bank aliasing)
#define CD   32                  // D-chunk per block
#define NCH  (DIMZ / CD)         // 5
#define NTH  (DIMY / TS)         // 10
#define NTW  (DIMX / TS)         // 10
#define NBLK (NCH * BC * NTH * NTW)  // 1000 blocks

static_assert(NTOT == 8192000, "size mismatch");

// Ring slot update with compile-time index K (keeps ring[][] in VGPRs).
#define RING_CASE(K) case K: {                                         \
    _Pragma("unroll")                                                  \
    for (int f = 0; f < 5; ++f) {                                      \
      sums[f] += S[f] - ring[K][f];                                    \
      ring[K][f] = S[f];                                               \
    }                                                                  \
  } break;

__global__ __launch_bounds__(256) void fused_ssim(const float* __restrict__ X,
                                                  const float* __restrict__ Y,
                                                  float* __restrict__ pssim,
                                                  float* __restrict__ pl1) {
  __shared__ float4 xs4[HS * XS4];   // raw x slab, 26 rows x 10 float4 (cols w0-8..w0+23)
  __shared__ float4 ys4[HS * XS4];
  __shared__ float4 wp4[HS * WPS];   // W-passed {sx,sy,sxx,syy}, stride 17
  __shared__ float  wp1[HS * WPS];   // W-passed sxy, stride 17

  float* xsf = (float*)xs4;
  float* ysf = (float*)ys4;

  const int tid = threadIdx.x;
  const int bx  = blockIdx.x;
  const int tw  = bx % NTW;
  const int th  = (bx / NTW) % NTH;
  const int b   = (bx / (NTW * NTH)) % BC;
  const int ch  =  bx / (NTW * NTH * BC);
  const int h0 = th * TS, w0 = tw * TS, c0 = ch * CD;
  const size_t bbase = (size_t)b * (DIMZ * DIMY * DIMX);

  const int hh = tid >> 4, ww = tid & 15;     // H-pass / output ownership
  const int sr = tid >> 3, sc4 = tid & 7;     // staging (tid < 208): row 0..25, col4 0..7
  const int sgh = h0 - PAD + sr;
  const int sgw = w0 - 8 + (sc4 << 2);        // global col of float4 (multiple of 4)
  const bool sin_ = ((unsigned)sgh < (unsigned)DIMY) && ((unsigned)sgw < (unsigned)DIMX);
  const int wr = tid >> 2, wg = tid & 3;      // W-pass (tid < 104): row 0..25, out-group 0..3

  float ring[11][5];
#pragma unroll
  for (int k = 0; k < 11; ++k)
#pragma unroll
    for (int f = 0; f < 5; ++f) ring[k][f] = 0.f;
  float sums[5] = {0.f, 0.f, 0.f, 0.f, 0.f};
  float l1loc = 0.f, ssloc = 0.f;

  const float inv = 1.0f / 1331.0f;             // 1/11^3
  const float c1  = 0.01f / (4096.f * 4096.f);  // K1 / data_range^2 (faithful to ref)
  const float c2  = 0.03f / (4096.f * 4096.f);

  int ph = ((c0 - PAD) + 22) % 11;   // uniform ring phase

  for (int d = c0 - PAD; d <= c0 + CD + PAD - 1; ++d) {
    float S[5] = {0.f, 0.f, 0.f, 0.f, 0.f};
    if ((unsigned)d < (unsigned)DIMZ) {
      const size_t dbase = bbase + (size_t)d * (DIMY * DIMX);
      const bool dIn = (d >= c0) && (d < c0 + CD);

      __syncthreads();  // prev slab's wp/xsl readers must finish before overwrite

      // --- stage: 26 rows x 8 float4 of x and y (zero OOB), b128 writes ---
      if (tid < 208) {
        float4 xv = {0.f, 0.f, 0.f, 0.f}, yv = {0.f, 0.f, 0.f, 0.f};
        if (sin_) {
          const size_t g = dbase + (size_t)sgh * DIMX + sgw;
          xv = *(const float4*)(X + g);
          yv = *(const float4*)(Y + g);
        }
        xs4[sr * XS4 + sc4] = xv;
        ys4[sr * XS4 + sc4] = yv;
      }
      __syncthreads();

      // --- W-pass: 104 threads x 4 sliding outputs; b128 LDS reads ---
      if (tid < 104) {
        float xv[17], yv[17];
        const int b4 = wr * XS4 + wg;
        float4 t;
        t = xs4[b4];     xv[0]=t.x;  xv[1]=t.y;  xv[2]=t.z;  xv[3]=t.w;
        t = xs4[b4 + 1]; xv[4]=t.x;  xv[5]=t.y;  xv[6]=t.z;  xv[7]=t.w;
        t = xs4[b4 + 2]; xv[8]=t.x;  xv[9]=t.y;  xv[10]=t.z; xv[11]=t.w;
        t = xs4[b4 + 3]; xv[12]=t.x; xv[13]=t.y; xv[14]=t.z; xv[15]=t.w;
        xv[16] = xsf[wr * (XS4 * 4) + (wg << 2) + 16];
        t = ys4[b4];     yv[0]=t.x;  yv[1]=t.y;  yv[2]=t.z;  yv[3]=t.w;
        t = ys4[b4 + 1]; yv[4]=t.x;  yv[5]=t.y;  yv[6]=t.z;  yv[7]=t.w;
        t = ys4[b4 + 2]; yv[8]=t.x;  yv[9]=t.y;  yv[10]=t.z; yv[11]=t.w;
        t = ys4[b4 + 3]; yv[12]=t.x; yv[13]=t.y; yv[14]=t.z; yv[15]=t.w;
        yv[16] = ysf[wr * (XS4 * 4) + (wg << 2) + 16];

        // output w = 4*wg + k; window = local cols (k+3)..(k+13)
        float sx = 0.f, sy = 0.f, sxx = 0.f, syy = 0.f, sxy = 0.f;
#pragma unroll
        for (int j = 3; j <= 13; ++j) {
          sx += xv[j];
          sy += yv[j];
          sxx = fmaf(xv[j], xv[j], sxx);
          syy = fmaf(yv[j], yv[j], syy);
          sxy = fmaf(xv[j], yv[j], sxy);
        }
        const int o = wr * WPS + (wg << 2);
        wp4[o] = make_float4(sx, sy, sxx, syy);
        wp1[o] = sxy;
#pragma unroll
        for (int k = 1; k < 4; ++k) {
          const float xn = xv[k + 13], xo = xv[k + 2];
          const float yn = yv[k + 13], yo = yv[k + 2];
          sx += xn - xo;
          sy += yn - yo;
          sxx = fmaf(-xo, xo, fmaf(xn, xn, sxx));
          syy = fmaf(-yo, yo, fmaf(yn, yn, syy));
          sxy = fmaf(-xo, yo, fmaf(xn, yn, sxy));
          wp4[o + k] = make_float4(sx, sy, sxx, syy);
          wp1[o + k] = sxy;
        }
      }
      __syncthreads();

      // --- H-pass: 11 taps, b128 + b32 per tap; fused smooth-L1 on owned voxel ---
      float4 a4 = {0.f, 0.f, 0.f, 0.f};
      float  a1 = 0.f;
#pragma unroll
      for (int j = 0; j < 11; ++j) {
        const int o = (hh + j) * WPS + ww;
        const float4 v = wp4[o];
        a4.x += v.x; a4.y += v.y; a4.z += v.z; a4.w += v.w;
        a1 += wp1[o];
      }
      S[0] = a4.x; S[1] = a4.y; S[2] = a4.z; S[3] = a4.w; S[4] = a1;

      if (dIn) {
        const float xv0 = xsf[(hh + PAD) * (XS4 * 4) + ww + 8];
        const float yv0 = ysf[(hh + PAD) * (XS4 * 4) + ww + 8];
        const float ad = fabsf(xv0 - yv0);
        l1loc += (ad < 1.f) ? 0.5f * ad * ad : ad - 0.5f;
      }
    }

    // --- D-window ring update (registers, static index via uniform switch) ---
    switch (ph) {
      RING_CASE(0) RING_CASE(1) RING_CASE(2) RING_CASE(3) RING_CASE(4)
      RING_CASE(5) RING_CASE(6) RING_CASE(7) RING_CASE(8) RING_CASE(9)
      RING_CASE(10)
    }
    ph = (ph == 10) ? 0 : ph + 1;

    // --- SSIM for output voxel dc = d-5 ---
    if (d >= c0 + PAD) {
      const float mux = sums[0] * inv, muy = sums[1] * inv;
      const float exx = sums[2] * inv, eyy = sums[3] * inv, exy = sums[4] * inv;
      const float mux2 = mux * mux, muy2 = muy * muy, muxy = mux * muy;
      const float vx = exx - mux2, vy = eyy - muy2, vxy = exy - muxy;
      const float nnum = (2.f * muxy + c1) * (2.f * vxy + c2);
      const float dden = (mux2 + muy2 + c1) * (vx + vy + c2);
      const float ssim = nnum * __builtin_amdgcn_rcpf(dden + 1e-8f);
      const float val  = 0.5f * (1.f - ssim);
      ssloc += fminf(fmaxf(val, 0.f), 1.f);
    }
  }

  // --- block reduction -> per-block partials ---
#pragma unroll
  for (int off = 32; off > 0; off >>= 1) {
    ssloc += __shfl_down(ssloc, off, 64);
    l1loc += __shfl_down(l1loc, off, 64);
  }
  __syncthreads();                 // LDS compute use done; reuse xsf as scratch
  const int lane = tid & 63, wv = tid >> 6;
  if (lane == 0) {
    xsf[wv * 2]     = ssloc;
    xsf[wv * 2 + 1] = l1loc;
  }
  __syncthreads();
  if (tid == 0) {
    pssim[bx] = xsf[0] + xsf[2] + xsf[4] + xsf[6];
    pl1[bx]   = xsf[1] + xsf[3] + xsf[5] + xsf[7];
  }
}

// Final: reduce 1000 + 1000 partials in double, emit scalar loss.
__global__ __launch_bounds__(256) void final_reduce(const float* __restrict__ pssim,
                                                    const float* __restrict__ pl1,
                                                    float* __restrict__ out) {
  double s = 0.0, l = 0.0;
  for (int i = threadIdx.x; i < NBLK; i += 256) {
    s += (double)pssim[i];
    l += (double)pl1[i];
  }
#pragma unroll
  for (int off = 32; off > 0; off >>= 1) {
    s += __shfl_down(s, off, 64);
    l += __shfl_down(l, off, 64);
  }
  __shared__ double sm[8];
  const int lane = threadIdx.x & 63, wv = threadIdx.x >> 6;
  if (lane == 0) { sm[wv * 2] = s; sm[wv * 2 + 1] = l; }
  __syncthreads();
  if (threadIdx.x == 0) {
    const double ssm = (sm[0] + sm[2] + sm[4] + sm[6]) / (double)NTOT;
    const double l1m = (sm[1] + sm[3] + sm[5] + sm[7]) / (double)NTOT;
    out[0] = (float)(0.85 * ssm + 0.15 * l1m);
  }
}

extern "C" void kernel_launch(void* const* d_in, const int* in_sizes, int n_in,
                              void* d_out, int out_size, void* d_ws, size_t ws_size,
                              hipStream_t stream) {
  const float* X = (const float*)d_in[0];
  const float* Y = (const float*)d_in[1];
  float* out = (float*)d_out;

  float* pssim = (float*)d_ws;        // NBLK floats
  float* pl1   = pssim + NBLK;        // NBLK floats

  fused_ssim<<<NBLK, 256, 0, stream>>>(X, Y, pssim, pl1);
  final_reduce<<<1, 256, 0, stream>>>(pssim, pl1, out);
}

// Round 5
// 167.858 us; speedup vs baseline: 3.5030x; 1.2830x over previous
//
#include <hip/hip_runtime.h>

// Shape fixed by reference: (2,1,160,160,160) fp32, window 11, zero-pad box filter.
// Fields reduced via u=x+y, v=x-y: box{u, v, u^2, v^2} packed in one float4.
#define DIMX 160
#define DIMY 160
#define DIMZ 160
#define BC   2
#define NTOT (BC * DIMZ * DIMY * DIMX)   // 8,192,000
#define PAD  5
#define TS   16                  // tile size in H and W
#define HS   26                  // TS + 2*PAD rows
#define XS4  10                  // stage row stride in float4 (8 used + 2 pad for banking)
#define WPS  17                  // wp row stride in float4 (breaks bank aliasing)
#define CD   20                  // D-chunk per block
#define NCH  (DIMZ / CD)         // 8
#define NTH  (DIMY / TS)         // 10
#define NTW  (DIMX / TS)         // 10
#define NBLK (NCH * BC * NTH * NTW)  // 1600 blocks

static_assert(NTOT == 8192000, "size mismatch");

__device__ __forceinline__ float4 f4add(float4 a, float4 b) {
  return make_float4(a.x + b.x, a.y + b.y, a.z + b.z, a.w + b.w);
}
__device__ __forceinline__ float4 f4sub(float4 a, float4 b) {
  return make_float4(a.x - b.x, a.y - b.y, a.z - b.z, a.w - b.w);
}

// Ring slot update with compile-time index K (keeps ring[] in VGPRs).
#define RING_CASE(K) case K: {                 \
    sums = f4add(sums, f4sub(Sv, ring[K]));    \
    ring[K] = Sv;                              \
  } break;

__global__ __launch_bounds__(256) void fused_ssim(const float* __restrict__ X,
                                                  const float* __restrict__ Y,
                                                  float* __restrict__ pssim,
                                                  float* __restrict__ pl1) {
  __shared__ float4 us4[HS * XS4];   // staged u slab (26 rows x 8 used float4)
  __shared__ float4 vs4[HS * XS4];   // staged v slab
  __shared__ float4 wpf[HS * WPS];   // W-passed {su,sv,suu,svv}, stride 17
  __shared__ float4 Sb[TS * TS];     // H-passed per-voxel field vector

  const int tid = threadIdx.x;
  const int bx  = blockIdx.x;
  const int tw  = bx % NTW;
  const int th  = (bx / NTW) % NTH;
  const int b   = (bx / (NTW * NTH)) % BC;
  const int ch  =  bx / (NTW * NTH * BC);
  const int h0 = th * TS, w0 = tw * TS, c0 = ch * CD;
  const size_t bbase = (size_t)b * (DIMZ * DIMY * DIMX);

  // staging decomposition: 208 threads = 26 rows x 8 float4-cols (w0-8 .. w0+23)
  const int sr  = tid >> 3, sc4 = tid & 7;
  const int sgh = h0 - PAD + sr;
  const int sgw = w0 - 8 + (sc4 << 2);
  const bool sok = (tid < 208) && ((unsigned)sgh < (unsigned)DIMY) &&
                   ((unsigned)sgw < (unsigned)DIMX);
  const bool l1own = (sr >= PAD) && (sr < PAD + TS) && (sc4 >= 2) && (sc4 < 6);
  const size_t sgoff = bbase + (size_t)sgh * DIMX + sgw;   // only used when sok

  float4 ring[11];
#pragma unroll
  for (int k = 0; k < 11; ++k) ring[k] = make_float4(0.f, 0.f, 0.f, 0.f);
  float4 sums = make_float4(0.f, 0.f, 0.f, 0.f);
  float l1loc = 0.f, ssloc = 0.f;

  const float inv = 1.0f / 1331.0f;             // 1/11^3
  const float c1  = 0.01f / (4096.f * 4096.f);  // K1 / data_range^2 (faithful to ref)
  const float c2  = 0.03f / (4096.f * 4096.f);

  // prefetch first slab (d = c0-PAD) into regs
  float4 xq = make_float4(0.f, 0.f, 0.f, 0.f), yq = xq;
  if (sok && (unsigned)(c0 - PAD) < (unsigned)DIMZ) {
    const size_t g = sgoff + (size_t)(c0 - PAD) * (DIMY * DIMX);
    xq = *(const float4*)(X + g);
    yq = *(const float4*)(Y + g);
  }

  int ph = (c0 - PAD + 22) % 11;   // uniform ring phase

  for (int d = c0 - PAD; d < c0 + CD + PAD; ++d) {
    const bool dval = (unsigned)d < (unsigned)DIMZ;
    const bool dIn  = (d >= c0) && (d < c0 + CD);

    // --- stage u,v from prefetched regs; fuse smooth-L1; issue next prefetch ---
    if (tid < 208) {
      if (dval) {
        const float4 u = f4add(xq, yq);
        const float4 v = f4sub(xq, yq);
        us4[sr * XS4 + sc4] = u;
        vs4[sr * XS4 + sc4] = v;
        if (dIn && l1own) {
          const float a0 = fabsf(v.x), a1 = fabsf(v.y);
          const float a2 = fabsf(v.z), a3 = fabsf(v.w);
          l1loc += (a0 < 1.f) ? 0.5f * a0 * a0 : a0 - 0.5f;
          l1loc += (a1 < 1.f) ? 0.5f * a1 * a1 : a1 - 0.5f;
          l1loc += (a2 < 1.f) ? 0.5f * a2 * a2 : a2 - 0.5f;
          l1loc += (a3 < 1.f) ? 0.5f * a3 * a3 : a3 - 0.5f;
        }
      }
      const int dn = d + 1;
      if (sok && (unsigned)dn < (unsigned)DIMZ) {
        const size_t g = sgoff + (size_t)dn * (DIMY * DIMX);
        xq = *(const float4*)(X + g);   // in flight across the whole slab body
        yq = *(const float4*)(Y + g);
      } else {
        xq = make_float4(0.f, 0.f, 0.f, 0.f);
        yq = make_float4(0.f, 0.f, 0.f, 0.f);
      }
    }
    __syncthreads();

    // --- W-pass: 104 threads x 4 sliding outputs; 5 b128 reads per field ---
    if (dval && tid < 104) {
      const int wr = tid >> 2, wg = tid & 3;
      const int rb = wr * XS4 + wg;
      const int o  = wr * WPS + (wg << 2);
      float su[4], sv[4], suu[4], svv[4];
      float t[20];
      {  // field u
        float4 q;
        q = us4[rb    ]; t[0]=q.x;  t[1]=q.y;  t[2]=q.z;  t[3]=q.w;
        q = us4[rb + 1]; t[4]=q.x;  t[5]=q.y;  t[6]=q.z;  t[7]=q.w;
        q = us4[rb + 2]; t[8]=q.x;  t[9]=q.y;  t[10]=q.z; t[11]=q.w;
        q = us4[rb + 3]; t[12]=q.x; t[13]=q.y; t[14]=q.z; t[15]=q.w;
        q = us4[rb + 4]; t[16]=q.x; t[17]=q.y; t[18]=q.z; t[19]=q.w;
        float s = 0.f, ss = 0.f;
#pragma unroll
        for (int j = 3; j <= 13; ++j) { s += t[j]; ss = fmaf(t[j], t[j], ss); }
        su[0] = s; suu[0] = ss;
#pragma unroll
        for (int k = 1; k < 4; ++k) {
          const float nw = t[13 + k], od = t[2 + k];
          s += nw - od;
          ss = fmaf(nw, nw, fmaf(-od, od, ss));
          su[k] = s; suu[k] = ss;
        }
      }
      {  // field v
        float4 q;
        q = vs4[rb    ]; t[0]=q.x;  t[1]=q.y;  t[2]=q.z;  t[3]=q.w;
        q = vs4[rb + 1]; t[4]=q.x;  t[5]=q.y;  t[6]=q.z;  t[7]=q.w;
        q = vs4[rb + 2]; t[8]=q.x;  t[9]=q.y;  t[10]=q.z; t[11]=q.w;
        q = vs4[rb + 3]; t[12]=q.x; t[13]=q.y; t[14]=q.z; t[15]=q.w;
        q = vs4[rb + 4]; t[16]=q.x; t[17]=q.y; t[18]=q.z; t[19]=q.w;
        float s = 0.f, ss = 0.f;
#pragma unroll
        for (int j = 3; j <= 13; ++j) { s += t[j]; ss = fmaf(t[j], t[j], ss); }
        sv[0] = s; svv[0] = ss;
#pragma unroll
        for (int k = 1; k < 4; ++k) {
          const float nw = t[13 + k], od = t[2 + k];
          s += nw - od;
          ss = fmaf(nw, nw, fmaf(-od, od, ss));
          sv[k] = s; svv[k] = ss;
        }
      }
#pragma unroll
      for (int k = 0; k < 4; ++k)
        wpf[o + k] = make_float4(su[k], sv[k], suu[k], svv[k]);
    }
    __syncthreads();

    // --- H-pass: 64 threads x 4 sliding outputs (14 b128 reads, 4 b128 writes) ---
    if (dval && tid < 64) {
      const int g = tid >> 4, w = tid & 15;
      const int base = (g << 2) * WPS + w;
      const float4 T0 = wpf[base];
      const float4 T1 = wpf[base + WPS];
      const float4 T2 = wpf[base + 2 * WPS];
      float4 S = f4add(f4add(T0, T1), T2);
#pragma unroll
      for (int t = 3; t <= 10; ++t) S = f4add(S, wpf[base + t * WPS]);
      Sb[((g << 2) + 0) * TS + w] = S;
      S = f4sub(f4add(S, wpf[base + 11 * WPS]), T0);
      Sb[((g << 2) + 1) * TS + w] = S;
      S = f4sub(f4add(S, wpf[base + 12 * WPS]), T1);
      Sb[((g << 2) + 2) * TS + w] = S;
      S = f4sub(f4add(S, wpf[base + 13 * WPS]), T2);
      Sb[((g << 2) + 3) * TS + w] = S;
    }
    __syncthreads();

    // --- redistribute, D-window ring update (registers, uniform switch) ---
    float4 Sv = make_float4(0.f, 0.f, 0.f, 0.f);
    if (dval) Sv = Sb[tid];
    switch (ph) {
      RING_CASE(0) RING_CASE(1) RING_CASE(2) RING_CASE(3) RING_CASE(4)
      RING_CASE(5) RING_CASE(6) RING_CASE(7) RING_CASE(8) RING_CASE(9)
      RING_CASE(10)
    }
    ph = (ph == 10) ? 0 : ph + 1;

    // --- SSIM for output voxel dc = d-5 (u/v algebra) ---
    if (d >= c0 + PAD) {
      const float mu_u = sums.x * inv, mu_v = sums.y * inv;
      const float Euu  = sums.z * inv, Evv  = sums.w * inv;
      const float P = mu_u * mu_u, Q = mu_v * mu_v;
      const float sgu = Euu - P, sgv = Evv - Q;
      const float num = (0.5f * (P - Q) + c1) * (0.5f * (sgu - sgv) + c2);
      const float den = (0.5f * (P + Q) + c1) * (0.5f * (sgu + sgv) + c2);
      const float ssim = num * __builtin_amdgcn_rcpf(den + 1e-8f);
      const float val  = 0.5f * (1.f - ssim);
      ssloc += fminf(fmaxf(val, 0.f), 1.f);
    }
  }

  // --- block reduction -> per-block partials ---
#pragma unroll
  for (int off = 32; off > 0; off >>= 1) {
    ssloc += __shfl_down(ssloc, off, 64);
    l1loc += __shfl_down(l1loc, off, 64);
  }
  __syncthreads();                 // LDS compute use done; reuse us4 as scratch
  float* scr = (float*)us4;
  const int lane = tid & 63, wv = tid >> 6;
  if (lane == 0) {
    scr[wv * 2]     = ssloc;
    scr[wv * 2 + 1] = l1loc;
  }
  __syncthreads();
  if (tid == 0) {
    pssim[bx] = scr[0] + scr[2] + scr[4] + scr[6];
    pl1[bx]   = scr[1] + scr[3] + scr[5] + scr[7];
  }
}

// Final: reduce 1600 + 1600 partials in double, emit scalar loss.
__global__ __launch_bounds__(256) void final_reduce(const float* __restrict__ pssim,
                                                    const float* __restrict__ pl1,
                                                    float* __restrict__ out) {
  double s = 0.0, l = 0.0;
  for (int i = threadIdx.x; i < NBLK; i += 256) {
    s += (double)pssim[i];
    l += (double)pl1[i];
  }
#pragma unroll
  for (int off = 32; off > 0; off >>= 1) {
    s += __shfl_down(s, off, 64);
    l += __shfl_down(l, off, 64);
  }
  __shared__ double sm[8];
  const int lane = threadIdx.x & 63, wv = threadIdx.x >> 6;
  if (lane == 0) { sm[wv * 2] = s; sm[wv * 2 + 1] = l; }
  __syncthreads();
  if (threadIdx.x == 0) {
    const double ssm = (sm[0] + sm[2] + sm[4] + sm[6]) / (double)NTOT;
    const double l1m = (sm[1] + sm[3] + sm[5] + sm[7]) / (double)NTOT;
    out[0] = (float)(0.85 * ssm + 0.15 * l1m);
  }
}

extern "C" void kernel_launch(void* const* d_in, const int* in_sizes, int n_in,
                              void* d_out, int out_size, void* d_ws, size_t ws_size,
                              hipStream_t stream) {
  const float* X = (const float*)d_in[0];
  const float* Y = (const float*)d_in[1];
  float* out = (float*)d_out;

  float* pssim = (float*)d_ws;        // NBLK floats
  float* pl1   = pssim + NBLK;        // NBLK floats

  fused_ssim<<<NBLK, 256, 0, stream>>>(X, Y, pssim, pl1);
  final_reduce<<<1, 256, 0, stream>>>(pssim, pl1, out);
}